// Round 18
// baseline (256.493 us; speedup 1.0000x reference)
//
#include <hip/hip_runtime.h>
#include <hip/hip_bf16.h>

#define N_SEND 49152
#define N_REC  65536
#define N_EDGES 262144
#define D_MODEL 256
#define EDGE_IN 4
#define EDGE_OUT 64
#define LIN_IN 320
#define LIN_OUT 256
#define BATCH 2

#define GBM 32   // rows per block in node GEMM (4 waves, 3 blocks/CU)

typedef __attribute__((ext_vector_type(4))) float f32x4;
typedef __attribute__((ext_vector_type(8))) short bf16x8;

static __device__ __forceinline__ unsigned short f2bf(float f) {
    union { float f; unsigned u; } v; v.f = f;
    unsigned r = v.u + 0x7FFF + ((v.u >> 16) & 1);   // round-to-nearest-even
    return (unsigned short)(r >> 16);
}
static __device__ __forceinline__ float bf2f(unsigned short h) {
    union { unsigned u; float f; } v; v.u = ((unsigned)h) << 16; return v.f;
}

// async global->LDS, 16B per lane; LDS dest = wave-uniform base + lane*16
static __device__ __forceinline__ void async_copy16(void* lds_ptr, const void* g_ptr) {
    __builtin_amdgcn_global_load_lds(
        (const __attribute__((address_space(1))) void*)g_ptr,
        (__attribute__((address_space(3))) void*)lds_ptr, 16, 0, 0);
}

// ---------------------------------------------------------------------------
// Weight prep: w1t[n][k]=bf16(ff_w1[k][n]) (256x320), w2t (256x256),
// w2et[n][k]=bf16(ee_w2[k][n]) (64x64).
__global__ __launch_bounds__(256) void wprep(
    const float* __restrict__ w1, const float* __restrict__ w2,
    const float* __restrict__ ew2,
    unsigned short* __restrict__ w1t, unsigned short* __restrict__ w2t,
    unsigned short* __restrict__ w2et)
{
    const int tid = blockIdx.x * 256 + threadIdx.x;
    if (tid < 256 * LIN_IN) {
        const int n = tid / LIN_IN, k = tid - n * LIN_IN;
        w1t[tid] = f2bf(w1[k * LIN_OUT + n]);
    } else if (tid < 256 * LIN_IN + 256 * LIN_OUT) {
        const int t2 = tid - 256 * LIN_IN;
        const int n = t2 >> 8, k = t2 & 255;
        w2t[t2] = f2bf(w2[k * LIN_OUT + n]);
    } else if (tid < 256 * LIN_IN + 256 * LIN_OUT + EDGE_OUT * EDGE_OUT) {
        const int t3 = tid - (256 * LIN_IN + 256 * LIN_OUT);
        const int n = t3 >> 6, k = t3 & 63;
        w2et[t3] = f2bf(ew2[k * EDGE_OUT + n]);
    }
}

// ---------------------------------------------------------------------------
// Fused prep: [conv_x | edge MLP (MFMA, vectorized W2) + histogram].
__global__ __launch_bounds__(256) void prep_fused(
    const float* __restrict__ x, unsigned short* __restrict__ xb, int nconv,
    const int* __restrict__ receivers, const float* __restrict__ edge_attr,
    const float* __restrict__ ee_w1, const float* __restrict__ ee_b1,
    const unsigned short* __restrict__ w2et, const float* __restrict__ ee_b2,
    unsigned short* __restrict__ efs, int* __restrict__ counts)
{
    __shared__ __align__(16) unsigned short h_lds[256 * EDGE_OUT];   // 32 KB

    const int bid = blockIdx.x;
    const int tid = threadIdx.x;

    if (bid < nconv) {
        const size_t i = ((size_t)bid * 256 + tid) * 8;
        const float4 v0 = *(const float4*)&x[i];
        const float4 v1 = *(const float4*)&x[i + 4];
        bf16x8 o;
        o[0] = (short)f2bf(v0.x); o[1] = (short)f2bf(v0.y);
        o[2] = (short)f2bf(v0.z); o[3] = (short)f2bf(v0.w);
        o[4] = (short)f2bf(v1.x); o[5] = (short)f2bf(v1.y);
        o[6] = (short)f2bf(v1.z); o[7] = (short)f2bf(v1.w);
        *(bf16x8*)&xb[i] = o;
        return;
    }
    const int b2 = bid - nconv;

    {
        const int e0 = b2 * 256;
        atomicAdd(&counts[receivers[e0 + tid]], 1);

        {
            const float4 ea = *(const float4*)&edge_attr[(size_t)(e0 + tid) * EDGE_IN];
#pragma unroll
            for (int kb = 0; kb < 8; ++kb) {
                bf16x8 hv;
#pragma unroll
                for (int j = 0; j < 8; ++j) {
                    const int k = kb * 8 + j;
                    float a = ee_b1[k];
                    a += ea.x * ee_w1[0 * EDGE_OUT + k];
                    a += ea.y * ee_w1[1 * EDGE_OUT + k];
                    a += ea.z * ee_w1[2 * EDGE_OUT + k];
                    a += ea.w * ee_w1[3 * EDGE_OUT + k];
                    hv[j] = (short)f2bf(fmaxf(a, 0.0f));
                }
                *(bf16x8*)&h_lds[tid * EDGE_OUT + ((kb ^ (tid & 7)) * 8)] = hv;
            }
        }

        const int lane = tid & 63, wave = tid >> 6;
        const int n16 = lane & 15, hi = lane >> 4;

        bf16x8 bfr[2][4];
#pragma unroll
        for (int ch = 0; ch < 2; ++ch)
#pragma unroll
            for (int c = 0; c < 4; ++c)
                bfr[ch][c] = *(const bf16x8*)&w2et[(size_t)(16 * c + n16) * EDGE_OUT + ch * 32 + hi * 8];

        f32x4 acc[4][4];
#pragma unroll
        for (int c = 0; c < 4; ++c) {
            const float bv = ee_b2[16 * c + n16];
#pragma unroll
            for (int t = 0; t < 4; ++t) {
                acc[t][c][0] = bv; acc[t][c][1] = bv; acc[t][c][2] = bv; acc[t][c][3] = bv;
            }
        }

#pragma unroll
        for (int ch = 0; ch < 2; ++ch) {
            bf16x8 af[4];
#pragma unroll
            for (int t = 0; t < 4; ++t) {
                const int row = 64 * wave + 16 * t + n16;
                const int slot = (4 * ch + hi) ^ (row & 7);
                af[t] = *(const bf16x8*)&h_lds[row * EDGE_OUT + slot * 8];
            }
#pragma unroll
            for (int c = 0; c < 4; ++c)
#pragma unroll
                for (int t = 0; t < 4; ++t)
                    acc[t][c] = __builtin_amdgcn_mfma_f32_16x16x32_bf16(af[t], bfr[ch][c], acc[t][c], 0, 0, 0);
        }

#pragma unroll
        for (int t = 0; t < 4; ++t)
#pragma unroll
            for (int c = 0; c < 4; ++c)
#pragma unroll
                for (int r = 0; r < 4; ++r)
                    efs[(size_t)(e0 + 64 * wave + 16 * t + 4 * hi + r) * EDGE_OUT + 16 * c + n16] =
                        f2bf(acc[t][c][r]);
    }
}

// ---------------------------------------------------------------------------
// Exclusive scan of counts[65536] -> row_ptr[65537], copy to cursor.
__global__ __launch_bounds__(1024) void scan_kernel(
    const int* __restrict__ counts, int* __restrict__ row_ptr,
    int* __restrict__ cursor)
{
    __shared__ int sums[1024];
    const int t = threadIdx.x;
    const int4* c4 = (const int4*)(counts + t * 64);

    int s = 0;
#pragma unroll
    for (int i = 0; i < 16; ++i) { const int4 c = c4[i]; s += c.x + c.y + c.z + c.w; }
    sums[t] = s;
    __syncthreads();

    for (int off = 1; off < 1024; off <<= 1) {
        const int v = (t >= off) ? sums[t - off] : 0;
        __syncthreads();
        sums[t] += v;
        __syncthreads();
    }

    int run = sums[t] - s;
#pragma unroll
    for (int i = 0; i < 16; ++i) {
        const int4 c = c4[i];
        int4 w;
        w.x = run; w.y = run + c.x; w.z = w.y + c.y; w.w = w.z + c.z;
        run = w.w + c.w;
        ((int4*)(row_ptr + t * 64))[i] = w;
        ((int4*)(cursor + t * 64))[i] = w;
    }
    if (t == 1023) row_ptr[N_REC] = run;
}

// ---------------------------------------------------------------------------
// Bucket edges by receiver: one packed 8B store {edge, sender} per edge.
__global__ __launch_bounds__(256) void fill_kernel(
    const int* __restrict__ senders, const int* __restrict__ receivers,
    int* __restrict__ cursor, int2* __restrict__ eord2)
{
    const int e = blockIdx.x * 256 + threadIdx.x;
    const int r = receivers[e];
    const int pos = atomicAdd(&cursor[r], 1);
    eord2[pos] = make_int2(e, senders[e]);
}

// ---------------------------------------------------------------------------
// Wave-per-receiver gather, unroll-4 pipelined loads, packed int2 indices.
__global__ __launch_bounds__(256) void gather_kernel(
    const unsigned short* __restrict__ xb,
    const unsigned short* __restrict__ efs,
    const int* __restrict__ row_ptr,
    const int2* __restrict__ eord2,
    unsigned short* __restrict__ vmb)
{
    const int lane = threadIdx.x & 63;
    const int wave = threadIdx.x >> 6;
    const int r = blockIdx.x * 4 + wave;
    const int beg = row_ptr[r], end = row_ptr[r + 1];
    const int half = lane >> 5, l2 = lane & 31;
    const size_t xbase = (size_t)half * N_SEND * D_MODEL;

    float ax[8] = {0, 0, 0, 0, 0, 0, 0, 0};
    float ae[8] = {0, 0, 0, 0, 0, 0, 0, 0};

    for (int chunk = beg; chunk < end; chunk += 64) {
        const int n = min(64, end - chunk);
        int myidx = 0, myeidx = 0;
        if (chunk + lane < end) {
            const int2 p2 = eord2[chunk + lane];
            myeidx = p2.x; myidx = p2.y;
        }
        for (int i = 0; i < n; i += 4) {
            bf16x8 vx[4], ve[4];
#pragma unroll
            for (int u = 0; u < 4; ++u) {
                const int s = __shfl(myidx, i + u);
                const int e = __shfl(myeidx, i + u);
                const bool p = (i + u < n);
                const bf16x8 z = {0, 0, 0, 0, 0, 0, 0, 0};
                vx[u] = z; ve[u] = z;
                if (p) vx[u] = *(const bf16x8*)&xb[xbase + (size_t)s * D_MODEL + l2 * 8];
                if (p && lane < 8) ve[u] = *(const bf16x8*)&efs[(size_t)e * EDGE_OUT + lane * 8];
            }
#pragma unroll
            for (int u = 0; u < 4; ++u)
#pragma unroll
                for (int j = 0; j < 8; ++j)
                    ax[j] += bf2f((unsigned short)vx[u][j]);
            if (lane < 8) {
#pragma unroll
                for (int u = 0; u < 4; ++u)
#pragma unroll
                    for (int j = 0; j < 8; ++j)
                        ae[j] += bf2f((unsigned short)ve[u][j]);
            }
        }
    }

    bf16x8 o;
#pragma unroll
    for (int j = 0; j < 8; ++j) o[j] = (short)f2bf(ax[j]);
    *(bf16x8*)&vmb[((size_t)(half * N_REC + r)) * LIN_IN + l2 * 8] = o;
    if (lane < 8) {
        bf16x8 oe;
#pragma unroll
        for (int j = 0; j < 8; ++j) oe[j] = (short)f2bf(ae[j]);
        *(bf16x8*)&vmb[((size_t)r) * LIN_IN + D_MODEL + lane * 8] = oe;
        *(bf16x8*)&vmb[((size_t)(N_REC + r)) * LIN_IN + D_MODEL + lane * 8] = oe;
    }
}

// ---------------------------------------------------------------------------
// Node MLP, barrier-free steady state, GBM=32 -> 52KB LDS -> 3 blocks/CU
// (3 waves/SIMD, +50% TLP vs all prior variants at 2). Same proven swizzle
// paths; row-tile loop halved (t=0..1); A chunks 2KB; h (16KB) reuses A
// chunks 0-7. setprio(1) wraps MFMA clusters (T5: free-running waves have
// role diversity).
__global__ __launch_bounds__(256, 3) void node_mlp_fused(
    const unsigned short* __restrict__ vmb,   // [2*N_REC][320] bf16
    const unsigned short* __restrict__ w1t,   // [256][320] bf16
    const float* __restrict__ b1,
    const unsigned short* __restrict__ w2t,   // [256][256] bf16
    const float* __restrict__ b2,
    float* __restrict__ out)
{
    __shared__ __align__(16) char lds[53248];
    // [0,20480): A 10x2KB chunks (h reuses chunks 0-7)
    // [20480,53248): per-wave B dbuf: wave wc at 20480 + wc*8192 + buf*4096

    const int tid  = threadIdx.x;
    const int lane = tid & 63, wc = tid >> 6;
    const int n16  = lane & 15, hi = lane >> 4;
    const size_t row0 = (size_t)blockIdx.x * GBM;
    char* const wB = lds + 20480 + wc * 8192;

    const int f_l = (n16 & 3) ^ ((n16 >> 2) & 3);
    const int hsl = (hi ^ f_l) << 4;

    // stage A chunk kc (threads 0..127, 2KB, wire-format slot = g ^ f(row))
    auto stageA = [&](int kc) {
        if (tid < 128) {
            const int row = tid >> 2;            // 0..31
            const int sl = (tid & 3) ^ ((row & 3) ^ ((row >> 2) & 3));
            const unsigned short* g = vmb + (row0 + row) * LIN_IN + kc * 32 + sl * 8;
            char* l = lds + (kc << 11) + ((tid >> 6) << 10);
            async_copy16(l, g);
        }
    };
    auto issueB = [&](const unsigned short* BT, int ldk, int kk, int buf) {
#pragma unroll
        for (int p = 0; p < 4; ++p) {
            const int i = p * 64 + lane;
            const int row = i >> 2;              // 0..63
            const int sl = (i & 3) ^ ((row & 3) ^ ((row >> 2) & 3));
            const unsigned short* g = BT + (size_t)(64 * wc + row) * ldk + kk + sl * 8;
            char* l = wB + (buf << 12) + (p << 10);
            async_copy16(l, g);
        }
    };

    // ---- prologue: all of A + first B panel, one barrier ----
#pragma unroll
    for (int kc = 0; kc < LIN_IN / 32; ++kc) stageA(kc);
    issueB(w1t, LIN_IN, 0, 0);
    __syncthreads();

    // ---- Layer 1: K=320, 10 steps, NO barriers ----
    f32x4 acc[2][4];
#pragma unroll
    for (int c = 0; c < 4; ++c) {
        const float bv = b1[64 * wc + 16 * c + n16];
#pragma unroll
        for (int t = 0; t < 2; ++t) {
            acc[t][c][0] = bv; acc[t][c][1] = bv; acc[t][c][2] = bv; acc[t][c][3] = bv;
        }
    }

    int buf = 0;
    for (int step = 0; step < LIN_IN / 32; ++step) {
        if (step + 1 < LIN_IN / 32) {
            issueB(w1t, LIN_IN, (step + 1) * 32, buf ^ 1);
            __builtin_amdgcn_sched_barrier(0);
            asm volatile("s_waitcnt vmcnt(4)" ::: "memory");
        } else {
            asm volatile("s_waitcnt vmcnt(0)" ::: "memory");
        }
        __builtin_amdgcn_sched_barrier(0);

        bf16x8 af[2], bf[4];
        const char* Ab = lds + (step << 11);
        const char* Bb = wB + (buf << 12);
#pragma unroll
        for (int t = 0; t < 2; ++t)
            af[t] = *(const bf16x8*)(Ab + (16 * t + n16) * 64 + hsl);
#pragma unroll
        for (int c = 0; c < 4; ++c)
            bf[c] = *(const bf16x8*)(Bb + (16 * c + n16) * 64 + hsl);
        __builtin_amdgcn_s_setprio(1);
#pragma unroll
        for (int c = 0; c < 4; ++c)
#pragma unroll
            for (int t = 0; t < 2; ++t)
                acc[t][c] = __builtin_amdgcn_mfma_f32_16x16x32_bf16(af[t], bf[c], acc[t][c], 0, 0, 0);
        __builtin_amdgcn_s_setprio(0);
        buf ^= 1;
    }

    __syncthreads();   // all waves done reading A chunks (vmcnt already 0)

    issueB(w2t, LIN_OUT, 0, 0);   // flies across the next barrier

    // ---- h = relu(acc) -> A chunks 0-7, stage wire-format ----
#pragma unroll
    for (int t = 0; t < 2; ++t)
#pragma unroll
        for (int c = 0; c < 4; ++c) {
            const int col = 64 * wc + 16 * c + n16;
            const int kc = col >> 5;
            const int b  = (col & 31) * 2;
            const int gslot = b >> 4;
#pragma unroll
            for (int r = 0; r < 4; ++r) {
                const int lrow = 16 * t + 4 * hi + r;
                const int f = (lrow & 3) ^ ((lrow >> 2) & 3);
                *(unsigned short*)(lds + (kc << 11) + lrow * 64 + (((gslot ^ f) << 4) | (b & 15))) =
                    f2bf(fmaxf(acc[t][c][r], 0.0f));
            }
        }
    asm volatile("s_waitcnt lgkmcnt(0)" ::: "memory");
    __builtin_amdgcn_s_barrier();
    __builtin_amdgcn_sched_barrier(0);

    // ---- Layer 2: K=256, 8 steps, NO barriers ----
    f32x4 acc2[2][4];
#pragma unroll
    for (int c = 0; c < 4; ++c) {
        const float bv = b2[64 * wc + 16 * c + n16];
#pragma unroll
        for (int t = 0; t < 2; ++t) {
            acc2[t][c][0] = bv; acc2[t][c][1] = bv; acc2[t][c][2] = bv; acc2[t][c][3] = bv;
        }
    }

    buf = 0;
    for (int step = 0; step < LIN_OUT / 32; ++step) {
        if (step + 1 < LIN_OUT / 32) {
            issueB(w2t, LIN_OUT, (step + 1) * 32, buf ^ 1);
            __builtin_amdgcn_sched_barrier(0);
            asm volatile("s_waitcnt vmcnt(4)" ::: "memory");
        } else {
            asm volatile("s_waitcnt vmcnt(0)" ::: "memory");
        }
        __builtin_amdgcn_sched_barrier(0);

        bf16x8 af[2], bf[4];
        const char* Hb = lds + (step << 11);
        const char* Bb = wB + (buf << 12);
#pragma unroll
        for (int t = 0; t < 2; ++t)
            af[t] = *(const bf16x8*)(Hb + (16 * t + n16) * 64 + hsl);
#pragma unroll
        for (int c = 0; c < 4; ++c)
            bf[c] = *(const bf16x8*)(Bb + (16 * c + n16) * 64 + hsl);
        __builtin_amdgcn_s_setprio(1);
#pragma unroll
        for (int c = 0; c < 4; ++c)
#pragma unroll
            for (int t = 0; t < 2; ++t)
                acc2[t][c] = __builtin_amdgcn_mfma_f32_16x16x32_bf16(af[t], bf[c], acc2[t][c], 0, 0, 0);
        __builtin_amdgcn_s_setprio(0);
        buf ^= 1;
    }

#pragma unroll
    for (int t = 0; t < 2; ++t)
#pragma unroll
        for (int c = 0; c < 4; ++c)
#pragma unroll
            for (int r = 0; r < 4; ++r)
                out[(row0 + 16 * t + 4 * hi + r) * LIN_OUT + 64 * wc + 16 * c + n16] =
                    acc2[t][c][r];
}

// ---------------------------------------------------------------------------
extern "C" void kernel_launch(void* const* d_in, const int* in_sizes, int n_in,
                              void* d_out, int out_size, void* d_ws, size_t ws_size,
                              hipStream_t stream) {
    const float* x         = (const float*)d_in[0];
    const int*   edge_idx  = (const int*)d_in[1];
    const float* edge_attr = (const float*)d_in[2];
    const float* ee_w1     = (const float*)d_in[3];
    const float* ee_b1     = (const float*)d_in[4];
    const float* ee_w2     = (const float*)d_in[5];
    const float* ee_b2     = (const float*)d_in[6];
    const float* ff_w1     = (const float*)d_in[7];
    const float* ff_b1     = (const float*)d_in[8];
    const float* ff_w2     = (const float*)d_in[9];
    const float* ff_b2     = (const float*)d_in[10];
    float* out = (float*)d_out;

    const int* senders   = edge_idx;
    const int* receivers = edge_idx + N_EDGES;

    // Workspace layout (512B-aligned sub-buffers; ~172 MB, ws proven >= this).
    char* ws = (char*)d_ws;
    size_t off = 0;
    auto alloc = [&](size_t bytes) { char* p = ws + off; off += (bytes + 511) & ~511ull; return p; };

    unsigned short* vmb = (unsigned short*)alloc((size_t)BATCH * N_REC * LIN_IN * 2);   // 83.9 MB
    unsigned short* efs = (unsigned short*)alloc((size_t)N_EDGES * EDGE_OUT * 2);       // 33.6 MB
    unsigned short* xb  = (unsigned short*)alloc((size_t)BATCH * N_SEND * D_MODEL * 2); // 50.3 MB
    unsigned short* w1t = (unsigned short*)alloc((size_t)256 * LIN_IN * 2);
    unsigned short* w2t = (unsigned short*)alloc((size_t)256 * LIN_OUT * 2);
    unsigned short* w2et = (unsigned short*)alloc((size_t)EDGE_OUT * EDGE_OUT * 2);
    int* row_ptr        = (int*)alloc((size_t)(N_REC + 1) * 4);
    int* counts         = (int*)alloc((size_t)N_REC * 4);
    int* cursor         = (int*)alloc((size_t)N_REC * 4);
    int2* eord2         = (int2*)alloc((size_t)N_EDGES * 8);

    hipMemsetAsync(counts, 0, (size_t)N_REC * 4, stream);

    const int wprep_elems = 256 * LIN_IN + 256 * LIN_OUT + EDGE_OUT * EDGE_OUT;
    wprep<<<(wprep_elems + 255) / 256, 256, 0, stream>>>(
        ff_w1, ff_w2, ee_w2, w1t, w2t, w2et);

    const int nconv = (int)((size_t)BATCH * N_SEND * D_MODEL / 8 / 256);   // 12288
    prep_fused<<<nconv + N_EDGES / 256, 256, 0, stream>>>(
        x, xb, nconv, receivers, edge_attr, ee_w1, ee_b1, w2et, ee_b2, efs, counts);

    scan_kernel<<<1, 1024, 0, stream>>>(counts, row_ptr, cursor);

    fill_kernel<<<N_EDGES / 256, 256, 0, stream>>>(
        senders, receivers, cursor, eord2);

    gather_kernel<<<N_REC / 4, 256, 0, stream>>>(
        xb, efs, row_ptr, eord2, vmb);

    node_mlp_fused<<<(BATCH * N_REC) / GBM, 256, 0, stream>>>(
        vmb, w1t, ff_b1, w2t, ff_b2, out);
}

// Round 19
// 234.059 us; speedup vs baseline: 1.0958x; 1.0958x over previous
//
#include <hip/hip_runtime.h>
#include <hip/hip_bf16.h>

#define N_SEND 49152
#define N_REC  65536
#define N_EDGES 262144
#define D_MODEL 256
#define EDGE_IN 4
#define EDGE_OUT 64
#define LIN_IN 320
#define LIN_OUT 256
#define BATCH 2

#define GBM 64   // rows per block in node GEMM (4 waves, 2 blocks/CU)

typedef __attribute__((ext_vector_type(4))) float f32x4;
typedef __attribute__((ext_vector_type(8))) short bf16x8;

static __device__ __forceinline__ unsigned short f2bf(float f) {
    union { float f; unsigned u; } v; v.f = f;
    unsigned r = v.u + 0x7FFF + ((v.u >> 16) & 1);   // round-to-nearest-even
    return (unsigned short)(r >> 16);
}
static __device__ __forceinline__ float bf2f(unsigned short h) {
    union { unsigned u; float f; } v; v.u = ((unsigned)h) << 16; return v.f;
}

// async global->LDS, 16B per lane; LDS dest = wave-uniform base + lane*16
static __device__ __forceinline__ void async_copy16(void* lds_ptr, const void* g_ptr) {
    __builtin_amdgcn_global_load_lds(
        (const __attribute__((address_space(1))) void*)g_ptr,
        (__attribute__((address_space(3))) void*)lds_ptr, 16, 0, 0);
}

// ---------------------------------------------------------------------------
// Weight prep: w1t[n][k]=bf16(ff_w1[k][n]) (256x320), w2t (256x256),
// w2et[n][k]=bf16(ee_w2[k][n]) (64x64).
__global__ __launch_bounds__(256) void wprep(
    const float* __restrict__ w1, const float* __restrict__ w2,
    const float* __restrict__ ew2,
    unsigned short* __restrict__ w1t, unsigned short* __restrict__ w2t,
    unsigned short* __restrict__ w2et)
{
    const int tid = blockIdx.x * 256 + threadIdx.x;
    if (tid < 256 * LIN_IN) {
        const int n = tid / LIN_IN, k = tid - n * LIN_IN;
        w1t[tid] = f2bf(w1[k * LIN_OUT + n]);
    } else if (tid < 256 * LIN_IN + 256 * LIN_OUT) {
        const int t2 = tid - 256 * LIN_IN;
        const int n = t2 >> 8, k = t2 & 255;
        w2t[t2] = f2bf(w2[k * LIN_OUT + n]);
    } else if (tid < 256 * LIN_IN + 256 * LIN_OUT + EDGE_OUT * EDGE_OUT) {
        const int t3 = tid - (256 * LIN_IN + 256 * LIN_OUT);
        const int n = t3 >> 6, k = t3 & 63;
        w2et[t3] = f2bf(ew2[k * EDGE_OUT + n]);
    }
}

// ---------------------------------------------------------------------------
// Fused prep: [conv_x | edge MLP (MFMA, vectorized W2) + histogram].
__global__ __launch_bounds__(256) void prep_fused(
    const float* __restrict__ x, unsigned short* __restrict__ xb, int nconv,
    const int* __restrict__ receivers, const float* __restrict__ edge_attr,
    const float* __restrict__ ee_w1, const float* __restrict__ ee_b1,
    const unsigned short* __restrict__ w2et, const float* __restrict__ ee_b2,
    unsigned short* __restrict__ efs, int* __restrict__ counts)
{
    __shared__ __align__(16) unsigned short h_lds[256 * EDGE_OUT];   // 32 KB

    const int bid = blockIdx.x;
    const int tid = threadIdx.x;

    if (bid < nconv) {
        const size_t i = ((size_t)bid * 256 + tid) * 8;
        const float4 v0 = *(const float4*)&x[i];
        const float4 v1 = *(const float4*)&x[i + 4];
        bf16x8 o;
        o[0] = (short)f2bf(v0.x); o[1] = (short)f2bf(v0.y);
        o[2] = (short)f2bf(v0.z); o[3] = (short)f2bf(v0.w);
        o[4] = (short)f2bf(v1.x); o[5] = (short)f2bf(v1.y);
        o[6] = (short)f2bf(v1.z); o[7] = (short)f2bf(v1.w);
        *(bf16x8*)&xb[i] = o;
        return;
    }
    const int b2 = bid - nconv;

    {
        const int e0 = b2 * 256;
        atomicAdd(&counts[receivers[e0 + tid]], 1);

        {
            const float4 ea = *(const float4*)&edge_attr[(size_t)(e0 + tid) * EDGE_IN];
#pragma unroll
            for (int kb = 0; kb < 8; ++kb) {
                bf16x8 hv;
#pragma unroll
                for (int j = 0; j < 8; ++j) {
                    const int k = kb * 8 + j;
                    float a = ee_b1[k];
                    a += ea.x * ee_w1[0 * EDGE_OUT + k];
                    a += ea.y * ee_w1[1 * EDGE_OUT + k];
                    a += ea.z * ee_w1[2 * EDGE_OUT + k];
                    a += ea.w * ee_w1[3 * EDGE_OUT + k];
                    hv[j] = (short)f2bf(fmaxf(a, 0.0f));
                }
                *(bf16x8*)&h_lds[tid * EDGE_OUT + ((kb ^ (tid & 7)) * 8)] = hv;
            }
        }

        const int lane = tid & 63, wave = tid >> 6;
        const int n16 = lane & 15, hi = lane >> 4;

        bf16x8 bfr[2][4];
#pragma unroll
        for (int ch = 0; ch < 2; ++ch)
#pragma unroll
            for (int c = 0; c < 4; ++c)
                bfr[ch][c] = *(const bf16x8*)&w2et[(size_t)(16 * c + n16) * EDGE_OUT + ch * 32 + hi * 8];

        f32x4 acc[4][4];
#pragma unroll
        for (int c = 0; c < 4; ++c) {
            const float bv = ee_b2[16 * c + n16];
#pragma unroll
            for (int t = 0; t < 4; ++t) {
                acc[t][c][0] = bv; acc[t][c][1] = bv; acc[t][c][2] = bv; acc[t][c][3] = bv;
            }
        }

#pragma unroll
        for (int ch = 0; ch < 2; ++ch) {
            bf16x8 af[4];
#pragma unroll
            for (int t = 0; t < 4; ++t) {
                const int row = 64 * wave + 16 * t + n16;
                const int slot = (4 * ch + hi) ^ (row & 7);
                af[t] = *(const bf16x8*)&h_lds[row * EDGE_OUT + slot * 8];
            }
#pragma unroll
            for (int c = 0; c < 4; ++c)
#pragma unroll
                for (int t = 0; t < 4; ++t)
                    acc[t][c] = __builtin_amdgcn_mfma_f32_16x16x32_bf16(af[t], bfr[ch][c], acc[t][c], 0, 0, 0);
        }

#pragma unroll
        for (int t = 0; t < 4; ++t)
#pragma unroll
            for (int c = 0; c < 4; ++c)
#pragma unroll
                for (int r = 0; r < 4; ++r)
                    efs[(size_t)(e0 + 64 * wave + 16 * t + 4 * hi + r) * EDGE_OUT + 16 * c + n16] =
                        f2bf(acc[t][c][r]);
    }
}

// ---------------------------------------------------------------------------
// Exclusive scan of counts[65536] -> row_ptr[65537], copy to cursor.
__global__ __launch_bounds__(1024) void scan_kernel(
    const int* __restrict__ counts, int* __restrict__ row_ptr,
    int* __restrict__ cursor)
{
    __shared__ int sums[1024];
    const int t = threadIdx.x;
    const int4* c4 = (const int4*)(counts + t * 64);

    int s = 0;
#pragma unroll
    for (int i = 0; i < 16; ++i) { const int4 c = c4[i]; s += c.x + c.y + c.z + c.w; }
    sums[t] = s;
    __syncthreads();

    for (int off = 1; off < 1024; off <<= 1) {
        const int v = (t >= off) ? sums[t - off] : 0;
        __syncthreads();
        sums[t] += v;
        __syncthreads();
    }

    int run = sums[t] - s;
#pragma unroll
    for (int i = 0; i < 16; ++i) {
        const int4 c = c4[i];
        int4 w;
        w.x = run; w.y = run + c.x; w.z = w.y + c.y; w.w = w.z + c.z;
        run = w.w + c.w;
        ((int4*)(row_ptr + t * 64))[i] = w;
        ((int4*)(cursor + t * 64))[i] = w;
    }
    if (t == 1023) row_ptr[N_REC] = run;
}

// ---------------------------------------------------------------------------
// Bucket edges by receiver: one packed 8B store {edge, sender} per edge.
__global__ __launch_bounds__(256) void fill_kernel(
    const int* __restrict__ senders, const int* __restrict__ receivers,
    int* __restrict__ cursor, int2* __restrict__ eord2)
{
    const int e = blockIdx.x * 256 + threadIdx.x;
    const int r = receivers[e];
    const int pos = atomicAdd(&cursor[r], 1);
    eord2[pos] = make_int2(e, senders[e]);
}

// ---------------------------------------------------------------------------
// Wave-per-receiver gather, unroll-4 pipelined loads, packed int2 indices.
__global__ __launch_bounds__(256) void gather_kernel(
    const unsigned short* __restrict__ xb,
    const unsigned short* __restrict__ efs,
    const int* __restrict__ row_ptr,
    const int2* __restrict__ eord2,
    unsigned short* __restrict__ vmb)
{
    const int lane = threadIdx.x & 63;
    const int wave = threadIdx.x >> 6;
    const int r = blockIdx.x * 4 + wave;
    const int beg = row_ptr[r], end = row_ptr[r + 1];
    const int half = lane >> 5, l2 = lane & 31;
    const size_t xbase = (size_t)half * N_SEND * D_MODEL;

    float ax[8] = {0, 0, 0, 0, 0, 0, 0, 0};
    float ae[8] = {0, 0, 0, 0, 0, 0, 0, 0};

    for (int chunk = beg; chunk < end; chunk += 64) {
        const int n = min(64, end - chunk);
        int myidx = 0, myeidx = 0;
        if (chunk + lane < end) {
            const int2 p2 = eord2[chunk + lane];
            myeidx = p2.x; myidx = p2.y;
        }
        for (int i = 0; i < n; i += 4) {
            bf16x8 vx[4], ve[4];
#pragma unroll
            for (int u = 0; u < 4; ++u) {
                const int s = __shfl(myidx, i + u);
                const int e = __shfl(myeidx, i + u);
                const bool p = (i + u < n);
                const bf16x8 z = {0, 0, 0, 0, 0, 0, 0, 0};
                vx[u] = z; ve[u] = z;
                if (p) vx[u] = *(const bf16x8*)&xb[xbase + (size_t)s * D_MODEL + l2 * 8];
                if (p && lane < 8) ve[u] = *(const bf16x8*)&efs[(size_t)e * EDGE_OUT + lane * 8];
            }
#pragma unroll
            for (int u = 0; u < 4; ++u)
#pragma unroll
                for (int j = 0; j < 8; ++j)
                    ax[j] += bf2f((unsigned short)vx[u][j]);
            if (lane < 8) {
#pragma unroll
                for (int u = 0; u < 4; ++u)
#pragma unroll
                    for (int j = 0; j < 8; ++j)
                        ae[j] += bf2f((unsigned short)ve[u][j]);
            }
        }
    }

    bf16x8 o;
#pragma unroll
    for (int j = 0; j < 8; ++j) o[j] = (short)f2bf(ax[j]);
    *(bf16x8*)&vmb[((size_t)(half * N_REC + r)) * LIN_IN + l2 * 8] = o;
    if (lane < 8) {
        bf16x8 oe;
#pragma unroll
        for (int j = 0; j < 8; ++j) oe[j] = (short)f2bf(ae[j]);
        *(bf16x8*)&vmb[((size_t)r) * LIN_IN + D_MODEL + lane * 8] = oe;
        *(bf16x8*)&vmb[((size_t)(N_REC + r)) * LIN_IN + D_MODEL + lane * 8] = oe;
    }
}

// ---------------------------------------------------------------------------
// Fused node MLP, barrier-free steady state (round-13/17 verbatim, the only
// config measuring 81.7-84.9 us across six structural variants):
// A staged once (40KB wire-format), per-wave private B dbuf with counted
// vmcnt(4), 3 barriers total, GBM=64 / 4 waves / 72KB LDS -> 2 blocks/CU.
__global__ __launch_bounds__(256, 2) void node_mlp_fused(
    const unsigned short* __restrict__ vmb,   // [2*N_REC][320] bf16
    const unsigned short* __restrict__ w1t,   // [256][320] bf16
    const float* __restrict__ b1,
    const unsigned short* __restrict__ w2t,   // [256][256] bf16
    const float* __restrict__ b2,
    float* __restrict__ out)
{
    __shared__ __align__(16) char lds[73728];
    // [0,40960): A 10x4KB chunks (h reuses chunks 0-7 in layer 2)
    // [40960,73728): per-wave B dbuf: wave wc at 40960 + wc*8192 + buf*4096

    const int tid  = threadIdx.x;
    const int lane = tid & 63, wc = tid >> 6;
    const int n16  = lane & 15, hi = lane >> 4;
    const size_t row0 = (size_t)blockIdx.x * GBM;
    char* const wB = lds + 40960 + wc * 8192;

    const int f_l = (n16 & 3) ^ ((n16 >> 2) & 3);
    const int hsl = (hi ^ f_l) << 4;

    auto stageA = [&](int kc) {
        const int row = tid >> 2;
        const int sl = (tid & 3) ^ ((row & 3) ^ ((row >> 2) & 3));
        const unsigned short* g = vmb + (row0 + row) * LIN_IN + kc * 32 + sl * 8;
        char* l = lds + (kc << 12) + ((tid >> 6) << 10);
        async_copy16(l, g);
    };
    auto issueB = [&](const unsigned short* BT, int ldk, int kk, int buf) {
#pragma unroll
        for (int p = 0; p < 4; ++p) {
            const int i = p * 64 + lane;
            const int row = i >> 2;
            const int sl = (i & 3) ^ ((row & 3) ^ ((row >> 2) & 3));
            const unsigned short* g = BT + (size_t)(64 * wc + row) * ldk + kk + sl * 8;
            char* l = wB + (buf << 12) + (p << 10);
            async_copy16(l, g);
        }
    };

    // ---- prologue: all of A + first B panel, one barrier ----
#pragma unroll
    for (int kc = 0; kc < LIN_IN / 32; ++kc) stageA(kc);
    issueB(w1t, LIN_IN, 0, 0);
    __syncthreads();

    // ---- Layer 1: K=320, 10 steps, NO barriers ----
    f32x4 acc[4][4];
#pragma unroll
    for (int c = 0; c < 4; ++c) {
        const float bv = b1[64 * wc + 16 * c + n16];
#pragma unroll
        for (int t = 0; t < 4; ++t) {
            acc[t][c][0] = bv; acc[t][c][1] = bv; acc[t][c][2] = bv; acc[t][c][3] = bv;
        }
    }

    int buf = 0;
    for (int step = 0; step < LIN_IN / 32; ++step) {
        if (step + 1 < LIN_IN / 32) {
            issueB(w1t, LIN_IN, (step + 1) * 32, buf ^ 1);
            __builtin_amdgcn_sched_barrier(0);
            asm volatile("s_waitcnt vmcnt(4)" ::: "memory");
        } else {
            asm volatile("s_waitcnt vmcnt(0)" ::: "memory");
        }
        __builtin_amdgcn_sched_barrier(0);

        bf16x8 af[4], bf[4];
        const char* Ab = lds + (step << 12);
        const char* Bb = wB + (buf << 12);
#pragma unroll
        for (int t = 0; t < 4; ++t)
            af[t] = *(const bf16x8*)(Ab + (16 * t + n16) * 64 + hsl);
#pragma unroll
        for (int c = 0; c < 4; ++c)
            bf[c] = *(const bf16x8*)(Bb + (16 * c + n16) * 64 + hsl);
#pragma unroll
        for (int c = 0; c < 4; ++c)
#pragma unroll
            for (int t = 0; t < 4; ++t)
                acc[t][c] = __builtin_amdgcn_mfma_f32_16x16x32_bf16(af[t], bf[c], acc[t][c], 0, 0, 0);
        buf ^= 1;
    }

    __syncthreads();   // all waves done reading A chunks (vmcnt already 0)

    issueB(w2t, LIN_OUT, 0, 0);   // flies across the next barrier

    // ---- h = relu(acc) -> A chunks 0-7, stage wire-format ----
#pragma unroll
    for (int t = 0; t < 4; ++t)
#pragma unroll
        for (int c = 0; c < 4; ++c) {
            const int col = 64 * wc + 16 * c + n16;
            const int kc = col >> 5;
            const int b  = (col & 31) * 2;
            const int gslot = b >> 4;
#pragma unroll
            for (int r = 0; r < 4; ++r) {
                const int lrow = 16 * t + 4 * hi + r;
                const int f = (lrow & 3) ^ ((lrow >> 2) & 3);
                *(unsigned short*)(lds + (kc << 12) + lrow * 64 + (((gslot ^ f) << 4) | (b & 15))) =
                    f2bf(fmaxf(acc[t][c][r], 0.0f));
            }
        }
    asm volatile("s_waitcnt lgkmcnt(0)" ::: "memory");
    __builtin_amdgcn_s_barrier();
    __builtin_amdgcn_sched_barrier(0);

    // ---- Layer 2: K=256, 8 steps, NO barriers ----
    f32x4 acc2[4][4];
#pragma unroll
    for (int c = 0; c < 4; ++c) {
        const float bv = b2[64 * wc + 16 * c + n16];
#pragma unroll
        for (int t = 0; t < 4; ++t) {
            acc2[t][c][0] = bv; acc2[t][c][1] = bv; acc2[t][c][2] = bv; acc2[t][c][3] = bv;
        }
    }

    buf = 0;
    for (int step = 0; step < LIN_OUT / 32; ++step) {
        if (step + 1 < LIN_OUT / 32) {
            issueB(w2t, LIN_OUT, (step + 1) * 32, buf ^ 1);
            __builtin_amdgcn_sched_barrier(0);
            asm volatile("s_waitcnt vmcnt(4)" ::: "memory");
        } else {
            asm volatile("s_waitcnt vmcnt(0)" ::: "memory");
        }
        __builtin_amdgcn_sched_barrier(0);

        bf16x8 af[4], bf[4];
        const char* Hb = lds + (step << 12);
        const char* Bb = wB + (buf << 12);
#pragma unroll
        for (int t = 0; t < 4; ++t)
            af[t] = *(const bf16x8*)(Hb + (16 * t + n16) * 64 + hsl);
#pragma unroll
        for (int c = 0; c < 4; ++c)
            bf[c] = *(const bf16x8*)(Bb + (16 * c + n16) * 64 + hsl);
#pragma unroll
        for (int c = 0; c < 4; ++c)
#pragma unroll
            for (int t = 0; t < 4; ++t)
                acc2[t][c] = __builtin_amdgcn_mfma_f32_16x16x32_bf16(af[t], bf[c], acc2[t][c], 0, 0, 0);
        buf ^= 1;
    }

#pragma unroll
    for (int t = 0; t < 4; ++t)
#pragma unroll
        for (int c = 0; c < 4; ++c)
#pragma unroll
            for (int r = 0; r < 4; ++r)
                out[(row0 + 16 * t + 4 * hi + r) * LIN_OUT + 64 * wc + 16 * c + n16] =
                    acc2[t][c][r];
}

// ---------------------------------------------------------------------------
extern "C" void kernel_launch(void* const* d_in, const int* in_sizes, int n_in,
                              void* d_out, int out_size, void* d_ws, size_t ws_size,
                              hipStream_t stream) {
    const float* x         = (const float*)d_in[0];
    const int*   edge_idx  = (const int*)d_in[1];
    const float* edge_attr = (const float*)d_in[2];
    const float* ee_w1     = (const float*)d_in[3];
    const float* ee_b1     = (const float*)d_in[4];
    const float* ee_w2     = (const float*)d_in[5];
    const float* ee_b2     = (const float*)d_in[6];
    const float* ff_w1     = (const float*)d_in[7];
    const float* ff_b1     = (const float*)d_in[8];
    const float* ff_w2     = (const float*)d_in[9];
    const float* ff_b2     = (const float*)d_in[10];
    float* out = (float*)d_out;

    const int* senders   = edge_idx;
    const int* receivers = edge_idx + N_EDGES;

    // Workspace layout (512B-aligned sub-buffers; ~172 MB, ws proven >= this).
    char* ws = (char*)d_ws;
    size_t off = 0;
    auto alloc = [&](size_t bytes) { char* p = ws + off; off += (bytes + 511) & ~511ull; return p; };

    unsigned short* vmb = (unsigned short*)alloc((size_t)BATCH * N_REC * LIN_IN * 2);   // 83.9 MB
    unsigned short* efs = (unsigned short*)alloc((size_t)N_EDGES * EDGE_OUT * 2);       // 33.6 MB
    unsigned short* xb  = (unsigned short*)alloc((size_t)BATCH * N_SEND * D_MODEL * 2); // 50.3 MB
    unsigned short* w1t = (unsigned short*)alloc((size_t)256 * LIN_IN * 2);
    unsigned short* w2t = (unsigned short*)alloc((size_t)256 * LIN_OUT * 2);
    unsigned short* w2et = (unsigned short*)alloc((size_t)EDGE_OUT * EDGE_OUT * 2);
    int* row_ptr        = (int*)alloc((size_t)(N_REC + 1) * 4);
    int* counts         = (int*)alloc((size_t)N_REC * 4);
    int* cursor         = (int*)alloc((size_t)N_REC * 4);
    int2* eord2         = (int2*)alloc((size_t)N_EDGES * 8);

    hipMemsetAsync(counts, 0, (size_t)N_REC * 4, stream);

    const int wprep_elems = 256 * LIN_IN + 256 * LIN_OUT + EDGE_OUT * EDGE_OUT;
    wprep<<<(wprep_elems + 255) / 256, 256, 0, stream>>>(
        ff_w1, ff_w2, ee_w2, w1t, w2t, w2et);

    const int nconv = (int)((size_t)BATCH * N_SEND * D_MODEL / 8 / 256);   // 12288
    prep_fused<<<nconv + N_EDGES / 256, 256, 0, stream>>>(
        x, xb, nconv, receivers, edge_attr, ee_w1, ee_b1, w2et, ee_b2, efs, counts);

    scan_kernel<<<1, 1024, 0, stream>>>(counts, row_ptr, cursor);

    fill_kernel<<<N_EDGES / 256, 256, 0, stream>>>(
        senders, receivers, cursor, eord2);

    gather_kernel<<<N_REC / 4, 256, 0, stream>>>(
        xb, efs, row_ptr, eord2, vmb);

    node_mlp_fused<<<(BATCH * N_REC) / GBM, 256, 0, stream>>>(
        vmb, w1t, ff_b1, w2t, ff_b2, out);
}